// Round 1
// baseline (420.984 us; speedup 1.0000x reference)
//
#include <hip/hip_runtime.h>
#include <hip/hip_fp16.h>
#include <hip/hip_cooperative_groups.h>

namespace cg = cooperative_groups;

// Problem constants (match reference)
#define BB      2048
#define CC      1024
#define FF      128
#define NBLK    256      // == CU count: cooperative grid, 1 block/CU
#define RPB     8        // rows per block (NBLK*RPB == BB)
#define TPB     512      // 8 waves/block
#define NITER   10
#define SUBR    8        // colsum accumulator spreading (256/8 = 32-way)
#define SCALING_F (2048.0f / 100000.0f)

// Static device storage: no hipMalloc, safe under graph capture, fully
// rewritten every call (never stale-poisoned by the harness).
// NOTE: g_K is GONE — K lives in LDS for the whole kernel now.
__device__ float g_meanPart[NBLK];             // per-block D partial sums
__device__ float g_colsum[NITER * SUBR * CC];  // spread K^T u accumulators

// Single fused cooperative kernel:
//   phase0: zero colsum, stage user embs, load own D rows -> LDS, D partial
//           sum, dot-GEMM (dott) -- all before the first grid sync
//   phase1: s2 from meanPart, K = exp(5*dott[items] - s2*D) in place in LDS
//   10x   : v_t -> u -> colsum[t] (atomics) -> grid.sync
//   final : v10 from colsum[9], P = K * u10 (x) v10 -> out
__global__ void __launch_bounds__(TPB)
fused_sinkhorn(const int* __restrict__ users, const int* __restrict__ items,
               const float* __restrict__ D, const float* __restrict__ caps,
               const float* __restrict__ iemb, const float* __restrict__ uemb,
               float* __restrict__ out) {
    const int bid = blockIdx.x, tid = threadIdx.x;
    const int r0 = bid * RPB;

    // LDS: 4 + 16 + 32 KB = 52 KB/block -> fits, 1 block/CU
    __shared__ union { float ue[RPB][FF]; float v[CC]; } uv;  // GEMM then v
    __shared__ __half dott[RPB][CC];   // 16 KB (phase0 -> phase1 only)
    __shared__ float  Kt[RPB][CC];     // 32 KB: D staging, then K, to the end
    __shared__ float  ush[RPB];
    __shared__ float  red[TPB / 64];
    __shared__ float  s2sh;

    // ---------------- phase 0 (everything independent of grid) --------------
    // zero colsum accumulators (coherent stores -> visible at LLC to all XCDs)
    for (int i = bid * TPB + tid; i < NITER * SUBR * CC; i += NBLK * TPB)
        __hip_atomic_store(&g_colsum[i], 0.0f, __ATOMIC_RELAXED,
                           __HIP_MEMORY_SCOPE_AGENT);

    // stage 8 user embeddings (8 rows x 32 float4)
    if (tid < 256) {
        int r = tid >> 5, f4 = tid & 31;
        int u = users[r0 + r];
        ((float4*)uv.ue[r])[f4] = ((const float4*)(uemb + (size_t)u * FF))[f4];
    }

    // own D rows -> Kt (staging for phase1) + block partial sum for mean(D)
    const float4* Dg  = (const float4*)(D + ((size_t)r0 << 10));
    float4*       KtL = (float4*)Kt;
    float p = 0.0f;
    for (int i = tid; i < RPB * CC / 4; i += TPB) {
        float4 d = Dg[i];
        KtL[i] = d;
        p += d.x + d.y + d.z + d.w;
    }
    #pragma unroll
    for (int off = 32; off > 0; off >>= 1) p += __shfl_down(p, off, 64);
    if ((tid & 63) == 0) red[tid >> 6] = p;
    __syncthreads();                     // also publishes uv.ue for the GEMM
    if (tid == 0) {
        float s = 0.0f;
        #pragma unroll
        for (int k = 0; k < TPB / 64; ++k) s += red[k];
        __hip_atomic_store(&g_meanPart[bid], s, __ATOMIC_RELAXED,
                           __HIP_MEMORY_SCOPE_AGENT);
    }

    // dot GEMM: dott[r][j] = ue[r] . iemb[j]; iemb stays L2-resident
    const float4* us = (const float4*)uv.ue;
    #pragma unroll
    for (int jj = 0; jj < CC / TPB; ++jj) {
        int j = jj * TPB + tid;
        float acc[RPB] = {};
        const float4* ip = (const float4*)(iemb + (size_t)j * FF);
        for (int f4 = 0; f4 < FF / 4; ++f4) {
            float4 a = ip[f4];
            #pragma unroll
            for (int r = 0; r < RPB; ++r) {
                float4 b = us[r * (FF / 4) + f4];   // broadcast LDS read
                acc[r] += a.x * b.x + a.y * b.y + a.z * b.z + a.w * b.w;
            }
        }
        #pragma unroll
        for (int r = 0; r < RPB; ++r) dott[r][j] = __float2half(acc[r]);
    }

    cg::this_grid().sync();   // colsum zeros + meanPart visible; dott done

    // ---------------- phase 1: s2, K in place in LDS ------------------------
    if (tid < 64) {
        float s = 0.0f;
        #pragma unroll
        for (int k = 0; k < NBLK / 64; ++k)
            s += __hip_atomic_load(&g_meanPart[tid + 64 * k], __ATOMIC_RELAXED,
                                   __HIP_MEMORY_SCOPE_AGENT);
        #pragma unroll
        for (int off = 32; off > 0; off >>= 1) s += __shfl_down(s, off, 64);
        if (tid == 0) s2sh = 5.0f * (float)(BB * CC) / s;
    }
    __syncthreads();
    const float s2 = s2sh;
    const int4* it4 = (const int4*)(items + ((size_t)r0 << 10));
    for (int i = tid; i < RPB * CC / 4; i += TPB) {
        int4   iv = it4[i];
        float4 d  = KtL[i];                 // the staged D values
        int    r  = i >> 8;                 // (i*4)>>10
        float4 kv;
        kv.x = __expf(5.0f * __half2float(dott[r][iv.x]) - s2 * d.x);
        kv.y = __expf(5.0f * __half2float(dott[r][iv.y]) - s2 * d.y);
        kv.z = __expf(5.0f * __half2float(dott[r][iv.z]) - s2 * d.z);
        kv.w = __expf(5.0f * __half2float(dott[r][iv.w]) - s2 * d.w);
        KtL[i] = kv;                        // K now lives in LDS until the end
    }

    // ---------------- Sinkhorn iterations -----------------------------------
    for (int t = 0; t < NITER; ++t) {
        // v_t (redundant per block; v_0 = 1)
        if (t == 0) {
            for (int c = tid; c < CC; c += TPB) uv.v[c] = 1.0f;
        } else {
            float* base = g_colsum + (size_t)(t - 1) * SUBR * CC;
            for (int c = tid; c < CC; c += TPB) {
                float s = 0.0f;
                #pragma unroll
                for (int k = 0; k < SUBR; ++k)
                    s += __hip_atomic_load(&base[k * CC + c], __ATOMIC_RELAXED,
                                           __HIP_MEMORY_SCOPE_AGENT);
                uv.v[c] = caps[c] * SCALING_F / s;
            }
        }
        __syncthreads();   // also orders Kt build (t==0) / colsum reads

        // u_r = 1/(K v)_r : one wave per row
        {
            int r = tid >> 6, l = tid & 63;
            const float4* kr = (const float4*)Kt[r];
            const float4* v4 = (const float4*)uv.v;
            float pp = 0.0f;
            #pragma unroll
            for (int i2 = 0; i2 < 4; ++i2) {
                float4 k = kr[l + i2 * 64], v = v4[l + i2 * 64];
                pp += k.x * v.x + k.y * v.y + k.z * v.z + k.w * v.w;
            }
            #pragma unroll
            for (int off = 32; off > 0; off >>= 1) pp += __shfl_down(pp, off, 64);
            if (l == 0) ush[r] = 1.0f / pp;
        }
        __syncthreads();

        // colsum[t] += K^T u  (fire-and-forget device-scope atomics)
        float* cb = g_colsum + ((size_t)t * SUBR + (bid & (SUBR - 1))) * CC;
        for (int c = tid; c < CC; c += TPB) {
            float s = 0.0f;
            #pragma unroll
            for (int r = 0; r < RPB; ++r) s += Kt[r][c] * ush[r];
            atomicAdd(&cb[c], s);
        }

        cg::this_grid().sync();   // colsum[t] complete + visible
    }

    // ---------------- final: v10, P = K * u10 (x) v10 -----------------------
    // ush still holds u10 from iteration t=9 (no recompute needed)
    {
        float* base = g_colsum + (size_t)(NITER - 1) * SUBR * CC;
        for (int c = tid; c < CC; c += TPB) {
            float s = 0.0f;
            #pragma unroll
            for (int k = 0; k < SUBR; ++k)
                s += __hip_atomic_load(&base[k * CC + c], __ATOMIC_RELAXED,
                                       __HIP_MEMORY_SCOPE_AGENT);
            uv.v[c] = caps[c] * SCALING_F / s;
        }
    }
    __syncthreads();

    float4* o4 = (float4*)(out + ((size_t)r0 << 10));
    for (int i = tid; i < RPB * CC / 4; i += TPB) {
        int    r  = i >> 8;
        float4 k  = KtL[i];
        float  ur = ush[r];
        float4 v  = *(const float4*)&uv.v[(i * 4) & (CC - 1)];
        float4 pv;
        pv.x = k.x * ur * v.x;  pv.y = k.y * ur * v.y;
        pv.z = k.z * ur * v.z;  pv.w = k.w * ur * v.w;
        o4[i] = pv;
    }
}

extern "C" void kernel_launch(void* const* d_in, const int* in_sizes, int n_in,
                              void* d_out, int out_size, void* d_ws, size_t ws_size,
                              hipStream_t stream) {
    const int*   users = (const int*)d_in[0];
    const int*   items = (const int*)d_in[1];
    const float* D     = (const float*)d_in[2];
    const float* caps  = (const float*)d_in[3];
    const float* iemb  = (const float*)d_in[4];
    const float* uemb  = (const float*)d_in[5];
    float* out = (float*)d_out;

    void* args[] = { (void*)&users, (void*)&items, (void*)&D, (void*)&caps,
                     (void*)&iemb, (void*)&uemb, (void*)&out };
    hipLaunchCooperativeKernel((const void*)fused_sinkhorn,
                               dim3(NBLK), dim3(TPB), args, 0, stream);
}

// Round 2
// 216.207 us; speedup vs baseline: 1.9471x; 1.9471x over previous
//
#include <hip/hip_runtime.h>
#include <hip/hip_fp16.h>

// Problem constants (match reference)
#define BB      2048
#define CC      1024
#define FF      128
#define NBLK    256      // == CU count: cooperative grid, 1 block/CU
#define RPB     8        // rows per block (NBLK*RPB == BB)
#define TPB     512      // 8 waves/block
#define NITER   10
#define SUBR    8        // colsum accumulator spreading (256/8 = 32-way)
#define SCALING_F (2048.0f / 100000.0f)

// Static device storage: no hipMalloc, safe under graph capture, fully
// rewritten (or monotonic) every call.
__device__ unsigned g_bar;                     // monotonic barrier counter (never reset)
__device__ float g_meanPart[NBLK];             // per-block D partial sums
__device__ float g_colsum[NITER * SUBR * CC];  // spread K^T u accumulators

// Lightweight grid barrier. Correctness argument:
//  - all cross-block data (g_colsum, g_meanPart) is written AND read with
//    agent-scope atomics -> serviced at the IF coherence point, bypassing the
//    non-coherent per-XCD L2s. No cache writeback/invalidate needed (this is
//    what makes it ~10x cheaper than cg::grid.sync()'s acq-rel fence).
//  - __syncthreads() emits s_waitcnt vmcnt(0) before s_barrier, so every
//    wave's outstanding atomics have completed at IF before tid 0 arrives.
//  - monotonic counter: launch L's barrier k spans [x, x+NBLK); each arriver
//    computes its epoch base from the fetch_add return value. Never reset ->
//    no reset races across graph replays; stragglers always make progress.
__device__ __forceinline__ void grid_barrier(int tid) {
    __syncthreads();
    if (tid == 0) {
        unsigned c = __hip_atomic_fetch_add(&g_bar, 1u, __ATOMIC_RELAXED,
                                            __HIP_MEMORY_SCOPE_AGENT);
        unsigned target = (c / NBLK) * NBLK + NBLK;
        while ((int)(__hip_atomic_load(&g_bar, __ATOMIC_RELAXED,
                                       __HIP_MEMORY_SCOPE_AGENT) - target) < 0)
            ;
    }
    __syncthreads();
}

__global__ void __launch_bounds__(TPB)
fused_sinkhorn(const int* __restrict__ users, const int* __restrict__ items,
               const float* __restrict__ D, const float* __restrict__ caps,
               const float* __restrict__ iemb, const float* __restrict__ uemb,
               float* __restrict__ out) {
    const int bid = blockIdx.x, tid = threadIdx.x;
    const int r0 = bid * RPB;

    // LDS: 4 + 16 + 32 KB = 52 KB/block -> 1 block/CU
    __shared__ union { float ue[RPB][FF]; float v[CC]; } uv;  // GEMM then v
    __shared__ __half dott[RPB][CC];   // 16 KB (phase0 -> phase1 only)
    __shared__ float  Kt[RPB][CC];     // 32 KB: D staging, then K, to the end
    __shared__ float  ush[RPB];
    __shared__ float  red[TPB / 64];
    __shared__ float  s2sh;

    // ---------------- phase 0 (everything independent of grid) --------------
    // zero colsum accumulators (atomic stores -> land at IF, visible to all)
    for (int i = bid * TPB + tid; i < NITER * SUBR * CC; i += NBLK * TPB)
        __hip_atomic_store(&g_colsum[i], 0.0f, __ATOMIC_RELAXED,
                           __HIP_MEMORY_SCOPE_AGENT);

    // stage 8 user embeddings (8 rows x 32 float4)
    if (tid < 256) {
        int r = tid >> 5, f4 = tid & 31;
        int u = users[r0 + r];
        ((float4*)uv.ue[r])[f4] = ((const float4*)(uemb + (size_t)u * FF))[f4];
    }

    // own D rows -> Kt (staging for phase1) + block partial sum for mean(D)
    const float4* Dg  = (const float4*)(D + ((size_t)r0 << 10));
    float4*       KtL = (float4*)Kt;
    float p = 0.0f;
    for (int i = tid; i < RPB * CC / 4; i += TPB) {
        float4 d = Dg[i];
        KtL[i] = d;
        p += d.x + d.y + d.z + d.w;
    }
    #pragma unroll
    for (int off = 32; off > 0; off >>= 1) p += __shfl_down(p, off, 64);
    if ((tid & 63) == 0) red[tid >> 6] = p;
    __syncthreads();                     // also publishes uv.ue for the GEMM
    if (tid == 0) {
        float s = 0.0f;
        #pragma unroll
        for (int k = 0; k < TPB / 64; ++k) s += red[k];
        __hip_atomic_store(&g_meanPart[bid], s, __ATOMIC_RELAXED,
                           __HIP_MEMORY_SCOPE_AGENT);
    }

    // dot GEMM: dott[r][j] = ue[r] . iemb[j]; iemb stays L2-resident
    const float4* us = (const float4*)uv.ue;
    #pragma unroll
    for (int jj = 0; jj < CC / TPB; ++jj) {
        int j = jj * TPB + tid;
        float acc[RPB] = {};
        const float4* ip = (const float4*)(iemb + (size_t)j * FF);
        for (int f4 = 0; f4 < FF / 4; ++f4) {
            float4 a = ip[f4];
            #pragma unroll
            for (int r = 0; r < RPB; ++r) {
                float4 b = us[r * (FF / 4) + f4];   // broadcast LDS read
                acc[r] += a.x * b.x + a.y * b.y + a.z * b.z + a.w * b.w;
            }
        }
        #pragma unroll
        for (int r = 0; r < RPB; ++r) dott[r][j] = __float2half(acc[r]);
    }

    grid_barrier(tid);   // colsum zeros + meanPart complete at IF; dott done

    // ---------------- phase 1: s2, K in place in LDS ------------------------
    if (tid < 64) {
        float s = 0.0f;
        #pragma unroll
        for (int k = 0; k < NBLK / 64; ++k)
            s += __hip_atomic_load(&g_meanPart[tid + 64 * k], __ATOMIC_RELAXED,
                                   __HIP_MEMORY_SCOPE_AGENT);
        #pragma unroll
        for (int off = 32; off > 0; off >>= 1) s += __shfl_down(s, off, 64);
        if (tid == 0) s2sh = 5.0f * (float)(BB * CC) / s;
    }
    __syncthreads();
    const float s2 = s2sh;
    const int4* it4 = (const int4*)(items + ((size_t)r0 << 10));
    for (int i = tid; i < RPB * CC / 4; i += TPB) {
        int4   iv = it4[i];
        float4 d  = KtL[i];                 // the staged D values
        int    r  = i >> 8;                 // (i*4)>>10
        float4 kv;
        kv.x = __expf(5.0f * __half2float(dott[r][iv.x]) - s2 * d.x);
        kv.y = __expf(5.0f * __half2float(dott[r][iv.y]) - s2 * d.y);
        kv.z = __expf(5.0f * __half2float(dott[r][iv.z]) - s2 * d.z);
        kv.w = __expf(5.0f * __half2float(dott[r][iv.w]) - s2 * d.w);
        KtL[i] = kv;                        // K now lives in LDS until the end
    }

    // ---------------- Sinkhorn iterations -----------------------------------
    for (int t = 0; t < NITER; ++t) {
        // v_t (redundant per block; v_0 = 1)
        if (t == 0) {
            for (int c = tid; c < CC; c += TPB) uv.v[c] = 1.0f;
        } else {
            float* base = g_colsum + (size_t)(t - 1) * SUBR * CC;
            for (int c = tid; c < CC; c += TPB) {
                float s = 0.0f;
                #pragma unroll
                for (int k = 0; k < SUBR; ++k)
                    s += __hip_atomic_load(&base[k * CC + c], __ATOMIC_RELAXED,
                                           __HIP_MEMORY_SCOPE_AGENT);
                uv.v[c] = caps[c] * SCALING_F / s;
            }
        }
        __syncthreads();   // also orders Kt build (t==0) / colsum reads

        // u_r = 1/(K v)_r : one wave per row
        {
            int r = tid >> 6, l = tid & 63;
            const float4* kr = (const float4*)Kt[r];
            const float4* v4 = (const float4*)uv.v;
            float pp = 0.0f;
            #pragma unroll
            for (int i2 = 0; i2 < 4; ++i2) {
                float4 k = kr[l + i2 * 64], v = v4[l + i2 * 64];
                pp += k.x * v.x + k.y * v.y + k.z * v.z + k.w * v.w;
            }
            #pragma unroll
            for (int off = 32; off > 0; off >>= 1) pp += __shfl_down(pp, off, 64);
            if (l == 0) ush[r] = 1.0f / pp;
        }
        __syncthreads();

        // colsum[t] += K^T u  (fire-and-forget device-scope atomics -> IF)
        float* cb = g_colsum + ((size_t)t * SUBR + (bid & (SUBR - 1))) * CC;
        for (int c = tid; c < CC; c += TPB) {
            float s = 0.0f;
            #pragma unroll
            for (int r = 0; r < RPB; ++r) s += Kt[r][c] * ush[r];
            atomicAdd(&cb[c], s);
        }

        grid_barrier(tid);   // colsum[t] complete at IF + all blocks past
    }

    // ---------------- final: v10, P = K * u10 (x) v10 -----------------------
    // ush still holds u10 from iteration t=9 (no recompute needed)
    {
        float* base = g_colsum + (size_t)(NITER - 1) * SUBR * CC;
        for (int c = tid; c < CC; c += TPB) {
            float s = 0.0f;
            #pragma unroll
            for (int k = 0; k < SUBR; ++k)
                s += __hip_atomic_load(&base[k * CC + c], __ATOMIC_RELAXED,
                                       __HIP_MEMORY_SCOPE_AGENT);
            uv.v[c] = caps[c] * SCALING_F / s;
        }
    }
    __syncthreads();

    float4* o4 = (float4*)(out + ((size_t)r0 << 10));
    for (int i = tid; i < RPB * CC / 4; i += TPB) {
        int    r  = i >> 8;
        float4 k  = KtL[i];
        float  ur = ush[r];
        float4 v  = *(const float4*)&uv.v[(i * 4) & (CC - 1)];
        float4 pv;
        pv.x = k.x * ur * v.x;  pv.y = k.y * ur * v.y;
        pv.z = k.z * ur * v.z;  pv.w = k.w * ur * v.w;
        o4[i] = pv;
    }
}

extern "C" void kernel_launch(void* const* d_in, const int* in_sizes, int n_in,
                              void* d_out, int out_size, void* d_ws, size_t ws_size,
                              hipStream_t stream) {
    const int*   users = (const int*)d_in[0];
    const int*   items = (const int*)d_in[1];
    const float* D     = (const float*)d_in[2];
    const float* caps  = (const float*)d_in[3];
    const float* iemb  = (const float*)d_in[4];
    const float* uemb  = (const float*)d_in[5];
    float* out = (float*)d_out;

    void* args[] = { (void*)&users, (void*)&items, (void*)&D, (void*)&caps,
                     (void*)&iemb, (void*)&uemb, (void*)&out };
    // Cooperative launch: guarantees all 256 blocks are co-resident, which the
    // custom barrier requires. We just don't use cg::grid.sync()'s fences.
    hipLaunchCooperativeKernel((const void*)fused_sinkhorn,
                               dim3(NBLK), dim3(TPB), args, 0, stream);
}

// Round 3
// 190.904 us; speedup vs baseline: 2.2052x; 1.1325x over previous
//
#include <hip/hip_runtime.h>
#include <hip/hip_fp16.h>

// Problem constants (match reference)
#define BB      2048
#define CC      1024
#define FF      128
#define NBLK    256      // == CU count: 1 block/CU (capacity allows 2/CU)
#define RPB     8        // rows per block (NBLK*RPB == BB)
#define TPB     512      // 8 waves/block
#define NITER   10
#define SUBR    8        // colsum accumulator spreading (256/8 = 32-way)
#define SCALING_F (2048.0f / 100000.0f)

// Static device storage: no hipMalloc, safe under graph capture, fully
// rewritten (or monotonic) every call.
__device__ unsigned g_bar;                     // monotonic barrier counter (never reset)
__device__ float g_meanPart[NBLK];             // per-block D partial sums
__device__ float g_colsum[NITER * SUBR * CC];  // spread K^T u accumulators

// Lightweight grid barrier. Correctness argument:
//  - all cross-block data (g_colsum, g_meanPart) is written AND read with
//    agent-scope atomics -> serviced at the IF coherence point, bypassing the
//    non-coherent per-XCD L2s. No cache writeback/invalidate needed.
//  - __syncthreads() emits s_waitcnt vmcnt(0) before s_barrier, so every
//    wave's outstanding atomics have completed at IF before tid 0 arrives.
//  - monotonic counter: never reset -> no reset races across graph replays.
//  - co-residency: 256 blocks, 52.5 KB LDS & 8 waves each -> device capacity
//    is 2 blocks/CU (512 blocks); all 256 are resident before any spins.
__device__ __forceinline__ void grid_barrier(int tid) {
    __syncthreads();
    if (tid == 0) {
        unsigned c = __hip_atomic_fetch_add(&g_bar, 1u, __ATOMIC_RELAXED,
                                            __HIP_MEMORY_SCOPE_AGENT);
        unsigned target = (c / NBLK) * NBLK + NBLK;
        while ((int)(__hip_atomic_load(&g_bar, __ATOMIC_RELAXED,
                                       __HIP_MEMORY_SCOPE_AGENT) - target) < 0)
            ;
    }
    __syncthreads();
}

__global__ void __launch_bounds__(TPB)
fused_sinkhorn(const int* __restrict__ users, const int* __restrict__ items,
               const float* __restrict__ D, const float* __restrict__ caps,
               const float* __restrict__ iemb, const float* __restrict__ uemb,
               float* __restrict__ out) {
    const int bid = blockIdx.x, tid = threadIdx.x;
    const int r0 = bid * RPB;

    // LDS: 4 + 16 + 32 KB = 52 KB/block
    __shared__ union { float ue[RPB][FF]; float v[CC]; } uv;  // GEMM then v
    __shared__ __half dott[RPB][CC];   // 16 KB (phase0 -> phase1 only)
    __shared__ float  Kt[RPB][CC];     // 32 KB: D staging, then K, to the end
    __shared__ float  ush[RPB];
    __shared__ float  red[TPB / 64];
    __shared__ float  s2sh;

    // ---------------- phase 0 (everything independent of grid) --------------
    // zero colsum accumulators (atomic stores -> land at IF, visible to all)
    for (int i = bid * TPB + tid; i < NITER * SUBR * CC; i += NBLK * TPB)
        __hip_atomic_store(&g_colsum[i], 0.0f, __ATOMIC_RELAXED,
                           __HIP_MEMORY_SCOPE_AGENT);

    // stage 8 user embeddings (8 rows x 32 float4)
    if (tid < 256) {
        int r = tid >> 5, f4 = tid & 31;
        int u = users[r0 + r];
        ((float4*)uv.ue[r])[f4] = ((const float4*)(uemb + (size_t)u * FF))[f4];
    }

    // own D rows -> Kt (staging for phase1) + block partial sum for mean(D)
    const float4* Dg  = (const float4*)(D + ((size_t)r0 << 10));
    float4*       KtL = (float4*)Kt;
    float p = 0.0f;
    for (int i = tid; i < RPB * CC / 4; i += TPB) {
        float4 d = Dg[i];
        KtL[i] = d;
        p += d.x + d.y + d.z + d.w;
    }
    #pragma unroll
    for (int off = 32; off > 0; off >>= 1) p += __shfl_down(p, off, 64);
    if ((tid & 63) == 0) red[tid >> 6] = p;
    __syncthreads();                     // also publishes uv.ue for the GEMM
    if (tid == 0) {
        float s = 0.0f;
        #pragma unroll
        for (int k = 0; k < TPB / 64; ++k) s += red[k];
        __hip_atomic_store(&g_meanPart[bid], s, __ATOMIC_RELAXED,
                           __HIP_MEMORY_SCOPE_AGENT);
    }

    // dot GEMM: dott[r][j] = ue[r] . iemb[j]; iemb stays L2-resident
    const float4* us = (const float4*)uv.ue;
    #pragma unroll
    for (int jj = 0; jj < CC / TPB; ++jj) {
        int j = jj * TPB + tid;
        float acc[RPB] = {};
        const float4* ip = (const float4*)(iemb + (size_t)j * FF);
        for (int f4 = 0; f4 < FF / 4; ++f4) {
            float4 a = ip[f4];
            #pragma unroll
            for (int r = 0; r < RPB; ++r) {
                float4 b = us[r * (FF / 4) + f4];   // broadcast LDS read
                acc[r] += a.x * b.x + a.y * b.y + a.z * b.z + a.w * b.w;
            }
        }
        #pragma unroll
        for (int r = 0; r < RPB; ++r) dott[r][j] = __float2half(acc[r]);
    }

    grid_barrier(tid);   // colsum zeros + meanPart complete at IF; dott done

    // ---------------- phase 1: s2, K in place in LDS ------------------------
    if (tid < 64) {
        float s = 0.0f;
        #pragma unroll
        for (int k = 0; k < NBLK / 64; ++k)
            s += __hip_atomic_load(&g_meanPart[tid + 64 * k], __ATOMIC_RELAXED,
                                   __HIP_MEMORY_SCOPE_AGENT);
        #pragma unroll
        for (int off = 32; off > 0; off >>= 1) s += __shfl_down(s, off, 64);
        if (tid == 0) s2sh = 5.0f * (float)(BB * CC) / s;
    }
    __syncthreads();
    const float s2 = s2sh;
    const int4* it4 = (const int4*)(items + ((size_t)r0 << 10));
    for (int i = tid; i < RPB * CC / 4; i += TPB) {
        int4   iv = it4[i];
        float4 d  = KtL[i];                 // the staged D values
        int    r  = i >> 8;                 // (i*4)>>10
        float4 kv;
        kv.x = __expf(5.0f * __half2float(dott[r][iv.x]) - s2 * d.x);
        kv.y = __expf(5.0f * __half2float(dott[r][iv.y]) - s2 * d.y);
        kv.z = __expf(5.0f * __half2float(dott[r][iv.z]) - s2 * d.z);
        kv.w = __expf(5.0f * __half2float(dott[r][iv.w]) - s2 * d.w);
        KtL[i] = kv;                        // K now lives in LDS until the end
    }

    // ---------------- Sinkhorn iterations -----------------------------------
    for (int t = 0; t < NITER; ++t) {
        // v_t (redundant per block; v_0 = 1)
        if (t == 0) {
            for (int c = tid; c < CC; c += TPB) uv.v[c] = 1.0f;
        } else {
            float* base = g_colsum + (size_t)(t - 1) * SUBR * CC;
            for (int c = tid; c < CC; c += TPB) {
                float s = 0.0f;
                #pragma unroll
                for (int k = 0; k < SUBR; ++k)
                    s += __hip_atomic_load(&base[k * CC + c], __ATOMIC_RELAXED,
                                           __HIP_MEMORY_SCOPE_AGENT);
                uv.v[c] = caps[c] * SCALING_F / s;
            }
        }
        __syncthreads();   // also orders Kt build (t==0) / colsum reads

        // u_r = 1/(K v)_r : one wave per row
        {
            int r = tid >> 6, l = tid & 63;
            const float4* kr = (const float4*)Kt[r];
            const float4* v4 = (const float4*)uv.v;
            float pp = 0.0f;
            #pragma unroll
            for (int i2 = 0; i2 < 4; ++i2) {
                float4 k = kr[l + i2 * 64], v = v4[l + i2 * 64];
                pp += k.x * v.x + k.y * v.y + k.z * v.z + k.w * v.w;
            }
            #pragma unroll
            for (int off = 32; off > 0; off >>= 1) pp += __shfl_down(pp, off, 64);
            if (l == 0) ush[r] = 1.0f / pp;
        }
        __syncthreads();

        // colsum[t] += K^T u  (fire-and-forget device-scope atomics -> IF)
        float* cb = g_colsum + ((size_t)t * SUBR + (bid & (SUBR - 1))) * CC;
        for (int c = tid; c < CC; c += TPB) {
            float s = 0.0f;
            #pragma unroll
            for (int r = 0; r < RPB; ++r) s += Kt[r][c] * ush[r];
            atomicAdd(&cb[c], s);
        }

        grid_barrier(tid);   // colsum[t] complete at IF + all blocks past
    }

    // ---------------- final: v10, P = K * u10 (x) v10 -----------------------
    // ush still holds u10 from iteration t=9 (no recompute needed)
    {
        float* base = g_colsum + (size_t)(NITER - 1) * SUBR * CC;
        for (int c = tid; c < CC; c += TPB) {
            float s = 0.0f;
            #pragma unroll
            for (int k = 0; k < SUBR; ++k)
                s += __hip_atomic_load(&base[k * CC + c], __ATOMIC_RELAXED,
                                       __HIP_MEMORY_SCOPE_AGENT);
            uv.v[c] = caps[c] * SCALING_F / s;
        }
    }
    __syncthreads();

    float4* o4 = (float4*)(out + ((size_t)r0 << 10));
    for (int i = tid; i < RPB * CC / 4; i += TPB) {
        int    r  = i >> 8;
        float4 k  = KtL[i];
        float  ur = ush[r];
        float4 v  = *(const float4*)&uv.v[(i * 4) & (CC - 1)];
        float4 pv;
        pv.x = k.x * ur * v.x;  pv.y = k.y * ur * v.y;
        pv.z = k.z * ur * v.z;  pv.w = k.w * ur * v.w;
        o4[i] = pv;
    }
}

extern "C" void kernel_launch(void* const* d_in, const int* in_sizes, int n_in,
                              void* d_out, int out_size, void* d_ws, size_t ws_size,
                              hipStream_t stream) {
    const int*   users = (const int*)d_in[0];
    const int*   items = (const int*)d_in[1];
    const float* D     = (const float*)d_in[2];
    const float* caps  = (const float*)d_in[3];
    const float* iemb  = (const float*)d_in[4];
    const float* uemb  = (const float*)d_in[5];
    float* out = (float*)d_out;

    // Plain launch (graph-capture friendly). Co-residency of all 256 blocks
    // is guaranteed by capacity arithmetic (2 blocks/CU possible), which the
    // custom monotonic barrier requires.
    hipLaunchKernelGGL(fused_sinkhorn, dim3(NBLK), dim3(TPB), 0, stream,
                       users, items, D, caps, iemb, uemb, out);
}